// Round 18
// baseline (294.262 us; speedup 1.0000x reference)
//
#include <hip/hip_runtime.h>
#include <hip/hip_bf16.h>

#define N_NODES 6144
#define IN_F 256
#define N_HEADS 4
#define N_HID 64
#define JS 16
#define JLEN (N_NODES / JS)        // 384
#define NW (JLEN / 32)             // 12 iterations per chunk row
#define SMB 392                    // byte stride per row: 384 + 8 (u64-aligned)

typedef __attribute__((ext_vector_type(4))) float floatx4;
typedef _Float16 half2_t __attribute__((ext_vector_type(2)));
typedef _Float16 half8_t __attribute__((ext_vector_type(8)));
typedef __attribute__((ext_vector_type(4))) unsigned uint4_t;

// ---------------- Kernel 1: ht = h @ W (fp32); epilogue -> htF (f16 MFMA B-fragment layout),
//   srcv (f32), tE1pk/tE2pk = f16x2 pairs of exp(tgt), exp(0.2*tgt).
__global__ __launch_bounds__(256) void ht_gemm_kernel(
    const float* __restrict__ h, const float* __restrict__ W,
    const float* __restrict__ a, short* __restrict__ htF,
    float* __restrict__ srcv, unsigned* __restrict__ tE1pk, unsigned* __restrict__ tE2pk)
{
    __shared__ float As[32][34];
    __shared__ float Bs[32][68];
    __shared__ float redS[32][16];
    __shared__ float redT[32][16];
    __shared__ unsigned short eh1[32], eh2[32];

    const int head = blockIdx.y;
    const int i0 = blockIdx.x * 32;
    const int tid = threadIdx.x;
    const int tx = tid & 15, ty = tid >> 4;

    float acc[2][4] = {};

    for (int k0 = 0; k0 < IN_F; k0 += 32) {
        __syncthreads();
        {
            const int m = tid >> 3, kq = tid & 7;
            const float4 v = *(const float4*)(h + (i0 + m) * IN_F + k0 + kq * 4);
            As[kq*4+0][m] = v.x; As[kq*4+1][m] = v.y;
            As[kq*4+2][m] = v.z; As[kq*4+3][m] = v.w;
        }
        #pragma unroll
        for (int it = 0; it < 2; ++it) {
            int l = it * 256 + tid;
            int k = l >> 4, nq = l & 15;
            *(float4*)&Bs[k][nq*4] = *(const float4*)(W + (k0 + k) * 256 + head * 64 + nq * 4);
        }
        __syncthreads();
        #pragma unroll
        for (int kk = 0; kk < 32; ++kk) {
            const float2 av = *(const float2*)&As[kk][ty*2];
            const float4 bv = *(const float4*)&Bs[kk][tx*4];
            const float aa[2] = {av.x, av.y};
            const float bb[4] = {bv.x, bv.y, bv.z, bv.w};
            #pragma unroll
            for (int r = 0; r < 2; ++r)
                #pragma unroll
                for (int c = 0; c < 4; ++c)
                    acc[r][c] = fmaf(aa[r], bb[c], acc[r][c]);
        }
    }

    #pragma unroll
    for (int r = 0; r < 2; ++r)
        #pragma unroll
        for (int c2 = 0; c2 < 4; ++c2) {
            const int d = tx * 4 + c2;
            const int j = i0 + ty * 2 + r;
            const int jt = j >> 5, q = (j >> 3) & 3, u = j & 7;
            const int c = d >> 4, n = d & 15;
            const size_t F = (((((size_t)head * 192 + jt) * 4 + c) * 16 + n) * 4 + q) * 8 + u;
            const _Float16 hv = (_Float16)acc[r][c2];
            htF[F] = *(const short*)&hv;
        }

    float as_[4], at_[4];
    #pragma unroll
    for (int c = 0; c < 4; ++c) {
        as_[c] = a[head * 128 + tx * 4 + c];
        at_[c] = a[head * 128 + 64 + tx * 4 + c];
    }
    #pragma unroll
    for (int r = 0; r < 2; ++r) {
        float ps = 0.f, pt = 0.f;
        #pragma unroll
        for (int c = 0; c < 4; ++c) {
            ps = fmaf(acc[r][c], as_[c], ps);
            pt = fmaf(acc[r][c], at_[c], pt);
        }
        redS[ty*2+r][tx] = ps;
        redT[ty*2+r][tx] = pt;
    }
    __syncthreads();
    if (tid < 64) {
        const int row = tid & 31;
        const float* src = (tid < 32) ? &redS[row][0] : &redT[row][0];
        float s = 0.f;
        #pragma unroll
        for (int x = 0; x < 16; ++x) s += src[x];
        if (tid < 32) {
            srcv[head * N_NODES + i0 + row] = s;
        } else {
            const _Float16 E1 = (_Float16)__expf(s);
            const _Float16 E2 = (_Float16)__expf(0.2f * s);
            eh1[row] = *(const unsigned short*)&E1;
            eh2[row] = *(const unsigned short*)&E2;
        }
    }
    __syncthreads();
    if (tid < 16) {
        const unsigned v1 = (unsigned)eh1[2*tid] | ((unsigned)eh1[2*tid+1] << 16);
        const unsigned v2 = (unsigned)eh2[2*tid] | ((unsigned)eh2[2*tid+1] << 16);
        tE1pk[head * (N_NODES/2) + i0/2 + tid] = v1;
        tE2pk[head * (N_NODES/2) + i0/2 + tid] = v2;
    }
}

// ---------------- Kernel 2: fused adj->byte-mask + masked rank-1 softmax + PV.
// R15 body, JS=16: 1536 blocks at ~3 resident/CU -> block ROTATION mixes the staging
// (HBM) phase of incoming blocks with the compute (VALU/L2) phase of resident ones.
// launch_bounds(256,3) fixed -- (256,6) spills accumulators (R13: 2GB scratch).
__global__ __launch_bounds__(256, 3) void gat_main_kernel(
    const int* __restrict__ adj, const short* __restrict__ htF,
    const float* __restrict__ srcv, const unsigned* __restrict__ tE1pk,
    const unsigned* __restrict__ tE2pk,
    float* __restrict__ pnum, float* __restrict__ pden)
{
    __shared__ unsigned char smaskB[64 * SMB];   // 24.5 KB byte-mask (0x00/0xFF per j)

    const int bid = blockIdx.x;
    const int xcd = bid & 7;
    const int idx = bid >> 3;                    // 0..191
    const int jc = idx / 12;                     // 0..15
    const int rb0 = ((idx % 12) * 8 + xcd) * 64;

    const int lane = threadIdx.x;
    const int head = threadIdx.y;                // wave = head
    const int m = lane & 15, quad = lane >> 4;
    const int jbase = jc * JLEN;

    // ---- dense staging: 96 items = (row r, 256-j group cg in {0,1} covering 384 j? no:
    // JLEN=384 -> per row 384 ints = 1.5 groups of 256. Use 128-j groups: lane covers 2 ints.
    // item = (row r, 128-j group cg in 0..2); lane l covers j = cg*128 + l*2..+1 (int2, 512B/load)
    const int* adjb = adj + (size_t)rb0 * N_NODES + jbase + lane * 2;
    for (int k0 = 0; k0 < 48; k0 += 8) {         // 192 items, 48 per wave
        int2 v[8];
        #pragma unroll
        for (int s = 0; s < 8; ++s) {
            const int item = (k0 + s) * 4 + head;    // 0..191
            const int r = item / 3, cg = item % 3;   // 64 rows x 3 groups of 128 j
            v[s] = *(const int2*)(adjb + (size_t)r * N_NODES + cg * 128);
        }
        #pragma unroll
        for (int s = 0; s < 8; ++s) {
            const int item = (k0 + s) * 4 + head;
            const int r = item / 3, cg = item % 3;
            const unsigned short b = (unsigned short)((unsigned)(v[s].x | (v[s].y << 8)) * 255u);
            *(unsigned short*)(smaskB + r * SMB + cg * 128 + lane * 2) = b;
        }
    }
    __syncthreads();

    half2_t e1s[4], e2s[4];
    #pragma unroll
    for (int t = 0; t < 4; ++t) {
        const float sv = srcv[head * N_NODES + rb0 + t * 16 + m];
        const _Float16 a1 = (_Float16)__expf(sv);
        const _Float16 a2 = (_Float16)__expf(0.2f * sv);
        e1s[t] = (half2_t){a1, a1};
        e2s[t] = (half2_t){a2, a2};
    }

    const short* fb = htF + ((size_t)(head * 192 + (jbase >> 5)) * 4) * 512 + (m * 4 + quad) * 8;
    const unsigned char* mrow = smaskB + m * SMB + quad * 8;   // + t*16*SMB + w*32
    const unsigned* pe1 = tE1pk + head * (N_NODES/2) + (jbase >> 1);
    const unsigned* pe2 = tE2pk + head * (N_NODES/2) + (jbase >> 1);

    half8_t bones;
    #pragma unroll
    for (int u = 0; u < 8; ++u) bones[u] = (_Float16)1.0f;

    floatx4 accN[4][4];
    floatx4 accD[4];
    #pragma unroll
    for (int t = 0; t < 4; ++t) {
        accD[t] = (floatx4){0,0,0,0};
        #pragma unroll
        for (int c = 0; c < 4; ++c) accN[t][c] = (floatx4){0,0,0,0};
    }

    // depth-1 prefetch: b-fragments + E (global)
    half8_t bn[4];
    #pragma unroll
    for (int c = 0; c < 4; ++c) bn[c] = *(const half8_t*)(fb + c * 512);
    uint4_t E1n = *(const uint4_t*)(pe1 + quad * 4);
    uint4_t E2n = *(const uint4_t*)(pe2 + quad * 4);

    for (int w = 0; w < NW; ++w) {
        half8_t bc[4];
        #pragma unroll
        for (int c = 0; c < 4; ++c) bc[c] = bn[c];
        const uint4_t E1 = E1n, E2 = E2n;

        const int wn = (w + 1 < NW) ? (w + 1) : w;      // clamped prefetch
        #pragma unroll
        for (int c = 0; c < 4; ++c)
            bn[c] = *(const half8_t*)(fb + (size_t)wn * 2048 + c * 512);
        E1n = *(const uint4_t*)(pe1 + wn * 16 + quad * 4);
        E2n = *(const uint4_t*)(pe2 + wn * 16 + quad * 4);

        const unsigned E1a[4] = {E1.x, E1.y, E1.z, E1.w};
        const unsigned E2a[4] = {E2.x, E2.y, E2.z, E2.w};

        #pragma unroll
        for (int t = 0; t < 4; ++t) {
            // byte-mask u64 for this row-tile's 8 j; expand to halfword masks via v_perm
            const unsigned long long mB =
                *(const unsigned long long*)(mrow + t * (16*SMB) + w * 32);
            const unsigned mlo = (unsigned)mB, mhi = (unsigned)(mB >> 32);
            const unsigned k0 = __builtin_amdgcn_perm(0u, mlo, 0x01010000u);  // u0,u1
            const unsigned k1 = __builtin_amdgcn_perm(0u, mlo, 0x03030202u);  // u2,u3
            const unsigned k2 = __builtin_amdgcn_perm(0u, mhi, 0x01010000u);  // u4,u5
            const unsigned k3 = __builtin_amdgcn_perm(0u, mhi, 0x03030202u);  // u6,u7
            const unsigned ka[4] = {k0, k1, k2, k3};

            uint4_t af_u;
            #pragma unroll
            for (int p = 0; p < 4; ++p) {
                const half2_t p1 = __builtin_bit_cast(half2_t, E1a[p]) * e1s[t];
                const half2_t p2 = __builtin_bit_cast(half2_t, E2a[p]) * e2s[t];
                const half2_t mx = __builtin_elementwise_max(p1, p2); // exp(lrelu) = max of exps
                const unsigned r = __builtin_bit_cast(unsigned, mx) & ka[p];
                if (p == 0) af_u.x = r; else if (p == 1) af_u.y = r;
                else if (p == 2) af_u.z = r; else af_u.w = r;
            }
            const half8_t af = __builtin_bit_cast(half8_t, af_u);
            #pragma unroll
            for (int c = 0; c < 4; ++c)
                accN[t][c] = __builtin_amdgcn_mfma_f32_16x16x32_f16(af, bc[c], accN[t][c], 0, 0, 0);
            accD[t] = __builtin_amdgcn_mfma_f32_16x16x32_f16(af, bones, accD[t], 0, 0, 0);
        }
    }

    const int slot = jc * N_HEADS + head;
    #pragma unroll
    for (int t = 0; t < 4; ++t) {
        if (m == 0) {
            #pragma unroll
            for (int r = 0; r < 4; ++r)
                pden[slot * N_NODES + rb0 + t * 16 + quad * 4 + r] = accD[t][r];
        }
        #pragma unroll
        for (int r = 0; r < 4; ++r) {
            const int gi = rb0 + t * 16 + quad * 4 + r;
            float* np_ = pnum + ((size_t)slot * N_NODES + gi) * N_HID + m;
            np_[0]  = accN[t][0][r];
            np_[16] = accN[t][1][r];
            np_[32] = accN[t][2][r];
            np_[48] = accN[t][3][r];
        }
    }
}

// ---------------- Kernel 3: reduce j-chunks, divide, mean over heads (float4)
__global__ __launch_bounds__(256) void finalize_kernel(
    const float* __restrict__ pnum, const float* __restrict__ pden,
    float* __restrict__ out)
{
    const int idx = blockIdx.x * 256 + threadIdx.x;   // over N_NODES*16
    if (idx >= N_NODES * 16) return;
    const int i = idx >> 4;
    const int d4 = (idx & 15) * 4;
    float sx = 0.f, sy = 0.f, sz = 0.f, sw = 0.f;
    #pragma unroll
    for (int hh = 0; hh < N_HEADS; ++hh) {
        float nx = 0.f, ny = 0.f, nz = 0.f, nw_ = 0.f, ds = 0.f;
        for (int jc = 0; jc < JS; ++jc) {
            const int slot = jc * N_HEADS + hh;
            const float4 v = *(const float4*)(pnum + ((size_t)slot * N_NODES + i) * N_HID + d4);
            nx += v.x; ny += v.y; nz += v.z; nw_ += v.w;
            ds += pden[slot * N_NODES + i];
        }
        const float r = 1.0f / ds;
        sx += nx * r; sy += ny * r; sz += nz * r; sw += nw_ * r;
    }
    float4 o; o.x = 0.25f * sx; o.y = 0.25f * sy; o.z = 0.25f * sz; o.w = 0.25f * sw;
    *(float4*)(out + (size_t)i * N_HID + d4) = o;
}

extern "C" void kernel_launch(void* const* d_in, const int* in_sizes, int n_in,
                              void* d_out, int out_size, void* d_ws, size_t ws_size,
                              hipStream_t stream)
{
    const float* h   = (const float*)d_in[0];
    const int*   adj = (const int*)d_in[1];
    const float* W   = (const float*)d_in[2];
    const float* a   = (const float*)d_in[3];
    float* out = (float*)d_out;

    char* ws = (char*)d_ws;
    short* htF = (short*)ws;
    size_t off = (size_t)N_HEADS * N_HID * N_NODES * 2;              // 3.1 MB
    float* srcv = (float*)(ws + off);        off += (size_t)N_HEADS * N_NODES * 4;
    unsigned* tE1pk = (unsigned*)(ws + off); off += (size_t)N_HEADS * (N_NODES/2) * 4;
    unsigned* tE2pk = (unsigned*)(ws + off); off += (size_t)N_HEADS * (N_NODES/2) * 4;
    float* pnum = (float*)(ws + off);        off += (size_t)JS * N_HEADS * N_NODES * N_HID * 4;  // 100.7 MB
    float* pden = (float*)(ws + off);

    ht_gemm_kernel<<<dim3(N_NODES / 32, N_HEADS), 256, 0, stream>>>(h, W, a, htF, srcv, tE1pk, tE2pk);
    gat_main_kernel<<<1536, dim3(64, 4), 0, stream>>>(
        adj, htF, srcv, tE1pk, tE2pk, pnum, pden);
    finalize_kernel<<<dim3((N_NODES * 16 + 255) / 256), 256, 0, stream>>>(pnum, pden, out);
}